// Round 1
// baseline (861.783 us; speedup 1.0000x reference)
//
#include <hip/hip_runtime.h>
#include <math.h>

constexpr int NN = 50000;   // nodes
constexpr int EE = 800000;  // edges
constexpr int D  = 128;     // feature dim (in & out)
// effective GEMM K = 512 (t-direction folded into r-direction weights)

// ---------------------------------------------------------------------------
// Kernel 1: build Wt[512][128], k-major, with W_t folded into W_r.
// cat = [h, r, bt, l, t], t == r  =>  z = h@W0^T + r@(W1+W4)^T + bt@W2^T + l@W3^T
// Wt[k][o] = W[o][k]  (+ W[o][k+384] when 128 <= k < 256)
// ---------------------------------------------------------------------------
__global__ __launch_bounds__(256) void prep_w(const float* __restrict__ W,
                                              float* __restrict__ Wt)
{
    int idx = blockIdx.x * 256 + threadIdx.x;  // 0 .. 512*128-1
    int k = idx >> 7;
    int o = idx & 127;
    float v = W[o * 640 + k];
    if (k >= 128 && k < 256) v += W[o * 640 + k + 384];
    Wt[idx] = v;  // idx == k*128 + o
}

// ---------------------------------------------------------------------------
// Kernel 2: edge scatter-aggregation. One wave (64 lanes) per edge.
// agg layout: [3][NN][128] f32 (zeroed via hipMemsetAsync before launch).
// positions==3 edges contribute to nothing -> skipped.
// ---------------------------------------------------------------------------
__global__ __launch_bounds__(256) void edge_agg(const float* __restrict__ h,
                                                const float* __restrict__ dist,
                                                const int* __restrict__ src,
                                                const int* __restrict__ dst,
                                                const int* __restrict__ pos,
                                                float* __restrict__ agg)
{
    int e = (blockIdx.x * 256 + threadIdx.x) >> 6;
    if (e >= EE) return;
    int p = pos[e];
    if (p == 3) return;
    int lane = threadIdx.x & 63;
    int s = src[e];
    int d = dst[e];
    float w = dist[e];
    float2 v = ((const float2*)(h + (size_t)s * D))[lane];  // 512B coalesced/wave
    float* outp = agg + ((size_t)p * NN + d) * D + lane * 2;
    unsafeAtomicAdd(outp,     v.x * w);   // global_atomic_add_f32
    unsafeAtomicAdd(outp + 1, v.y * w);
}

// ---------------------------------------------------------------------------
// Kernel 3: fused GEMM (M=NN, N=128, K=512) + bias + LayerNorm + ReLU.
// Block: 256 threads, tile 64 rows x 128 cols, Kc = 64.
// Thread (r = t/16, c = t%16) owns rows {r+16i}, cols {8c..8c+7}: acc[4][8].
// LDS: Xs[64][68] (pad 4 -> conflict-free bcast reads, 16B-aligned rows),
//      Ws[64][128] (k-major; 16B reads, 2-way bank alias = free).
// ---------------------------------------------------------------------------
__global__ __launch_bounds__(256) void gemm_ln(const float* __restrict__ h,
                                               const float* __restrict__ agg,
                                               const float* __restrict__ Wt,
                                               const float* __restrict__ bias,
                                               const float* __restrict__ gamma,
                                               const float* __restrict__ beta,
                                               float* __restrict__ out)
{
    __shared__ float Xs[64][68];
    __shared__ float Ws[64][128];
    const int t = threadIdx.x;
    const int r = t >> 4;
    const int c = t & 15;
    const int row0 = blockIdx.x * 64;

    float acc[4][8];
#pragma unroll
    for (int i = 0; i < 4; ++i)
#pragma unroll
        for (int j = 0; j < 8; ++j) acc[i][j] = 0.f;

    const float* xseg[4];
    xseg[0] = h;                           // k   0..127
    xseg[1] = agg;                         // k 128..255 (r, with t folded in)
    xseg[2] = agg + (size_t)NN * D;        // k 256..383 (bt)
    xseg[3] = agg + (size_t)2 * NN * D;    // k 384..511 (l)

    for (int kc = 0; kc < 8; ++kc) {
        const int k0 = kc * 64;
        const float* X = xseg[k0 >> 7];
        const int koff = k0 & 127;
        // stage X tile: 64x64, coalesced global read, linear LDS write
#pragma unroll
        for (int i = 0; i < 16; ++i) {
            int idx = t + 256 * i;
            int m = idx >> 6, kk = idx & 63;
            int row = row0 + m;
            Xs[m][kk] = (row < NN) ? X[(size_t)row * D + koff + kk] : 0.f;
        }
        // stage W tile: 64x128, coalesced (Wt is k-major), linear LDS write
#pragma unroll
        for (int i = 0; i < 32; ++i) {
            int idx = t + 256 * i;
            int kk = idx >> 7, o = idx & 127;
            Ws[kk][o] = Wt[(size_t)(k0 + kk) * D + o];
        }
        __syncthreads();
#pragma unroll
        for (int k = 0; k < 64; k += 4) {
            float4 xv[4];
#pragma unroll
            for (int i = 0; i < 4; ++i)
                xv[i] = *(const float4*)&Xs[r + 16 * i][k];
#pragma unroll
            for (int kk = 0; kk < 4; ++kk) {
                float4 w0 = *(const float4*)&Ws[k + kk][c * 8];
                float4 w1 = *(const float4*)&Ws[k + kk][c * 8 + 4];
#pragma unroll
                for (int i = 0; i < 4; ++i) {
                    float x = ((const float*)&xv[i])[kk];
                    acc[i][0] = fmaf(x, w0.x, acc[i][0]);
                    acc[i][1] = fmaf(x, w0.y, acc[i][1]);
                    acc[i][2] = fmaf(x, w0.z, acc[i][2]);
                    acc[i][3] = fmaf(x, w0.w, acc[i][3]);
                    acc[i][4] = fmaf(x, w1.x, acc[i][4]);
                    acc[i][5] = fmaf(x, w1.y, acc[i][5]);
                    acc[i][6] = fmaf(x, w1.z, acc[i][6]);
                    acc[i][7] = fmaf(x, w1.w, acc[i][7]);
                }
            }
        }
        __syncthreads();
    }

    // epilogue: +bias, LayerNorm over 128 cols (16-lane shfl reduce), ReLU
    float bb[8], gg[8], be[8];
    *(float4*)&bb[0] = *(const float4*)&bias[c * 8];
    *(float4*)&bb[4] = *(const float4*)&bias[c * 8 + 4];
    *(float4*)&gg[0] = *(const float4*)&gamma[c * 8];
    *(float4*)&gg[4] = *(const float4*)&gamma[c * 8 + 4];
    *(float4*)&be[0] = *(const float4*)&beta[c * 8];
    *(float4*)&be[4] = *(const float4*)&beta[c * 8 + 4];

#pragma unroll
    for (int i = 0; i < 4; ++i) {
        float s = 0.f, ss = 0.f;
#pragma unroll
        for (int j = 0; j < 8; ++j) {
            float z = acc[i][j] + bb[j];
            acc[i][j] = z;
            s += z;
            ss += z * z;
        }
        // lanes sharing the same r are 16 consecutive lanes within one wave
#pragma unroll
        for (int m = 1; m < 16; m <<= 1) {
            s  += __shfl_xor(s, m, 64);
            ss += __shfl_xor(ss, m, 64);
        }
        float mu  = s * (1.f / 128.f);
        float var = ss * (1.f / 128.f) - mu * mu;
        float rs  = rsqrtf(var + 1e-5f);
        int row = row0 + r + 16 * i;
        if (row < NN) {
            float o8[8];
#pragma unroll
            for (int j = 0; j < 8; ++j) {
                float v = (acc[i][j] - mu) * rs * gg[j] + be[j];
                o8[j] = v > 0.f ? v : 0.f;
            }
            float4* op = (float4*)&out[(size_t)row * D + c * 8];
            op[0] = *(float4*)&o8[0];
            op[1] = *(float4*)&o8[4];
        }
    }
}

// ---------------------------------------------------------------------------
extern "C" void kernel_launch(void* const* d_in, const int* in_sizes, int n_in,
                              void* d_out, int out_size, void* d_ws, size_t ws_size,
                              hipStream_t stream)
{
    const float* h     = (const float*)d_in[0];
    const float* dist  = (const float*)d_in[1];
    const float* W     = (const float*)d_in[2];
    const float* bias  = (const float*)d_in[3];
    const float* gamma = (const float*)d_in[4];
    const float* beta  = (const float*)d_in[5];
    const int*   src   = (const int*)d_in[6];
    const int*   dst   = (const int*)d_in[7];
    const int*   pos   = (const int*)d_in[8];

    float* agg = (float*)d_ws;                    // [3][NN][128] f32 = 76.8 MB
    float* Wt  = agg + (size_t)3 * NN * D;        // [512][128] f32  = 256 KB

    hipMemsetAsync(agg, 0, (size_t)3 * NN * D * sizeof(float), stream);
    prep_w<<<(512 * 128) / 256, 256, 0, stream>>>(W, Wt);
    edge_agg<<<(EE + 3) / 4, 256, 0, stream>>>(h, dist, src, dst, pos, agg);
    gemm_ln<<<(NN + 63) / 64, 256, 0, stream>>>(h, agg, Wt, bias, gamma, beta,
                                                (float*)d_out);
}

// Round 2
// 498.599 us; speedup vs baseline: 1.7284x; 1.7284x over previous
//
#include <hip/hip_runtime.h>
#include <math.h>
#include <stdint.h>

constexpr int NN = 50000;   // nodes
constexpr int EE = 800000;  // edges
constexpr int D  = 128;     // feature dim (in & out)
constexpr int NB = (NN + 255) / 256;  // scan blocks = 196

// ---------------------------------------------------------------------------
// Build Wt[512][128], k-major, with W_t folded into W_r.
// cat = [h, r, bt, l, t], t == r  =>  z = h@W0^T + r@(W1+W4)^T + bt@W2^T + l@W3^T
// ---------------------------------------------------------------------------
__global__ __launch_bounds__(256) void prep_w(const float* __restrict__ W,
                                              float* __restrict__ Wt)
{
    int idx = blockIdx.x * 256 + threadIdx.x;  // 0 .. 512*128-1
    int k = idx >> 7;
    int o = idx & 127;
    float v = W[o * 640 + k];
    if (k >= 128 && k < 256) v += W[o * 640 + k + 384];
    Wt[idx] = v;  // idx == k*128 + o
}

// ---------------------------------------------------------------------------
// CSR build: count -> 3-kernel exclusive scan -> fill (edge meta packed int2)
// ---------------------------------------------------------------------------
__global__ __launch_bounds__(256) void count_deg(const int* __restrict__ dst,
                                                 const int* __restrict__ pos,
                                                 int* __restrict__ deg)
{
    int e = blockIdx.x * 256 + threadIdx.x;
    if (e >= EE) return;
    if (pos[e] == 3) return;  // contributes to nothing
    atomicAdd(&deg[dst[e]], 1);
}

__global__ __launch_bounds__(256) void scan1(const int* __restrict__ deg,
                                             int* __restrict__ bsum)
{
    __shared__ int sm[256];
    int i = blockIdx.x * 256 + threadIdx.x;
    sm[threadIdx.x] = (i < NN) ? deg[i] : 0;
    __syncthreads();
    for (int s = 128; s > 0; s >>= 1) {
        if (threadIdx.x < s) sm[threadIdx.x] += sm[threadIdx.x + s];
        __syncthreads();
    }
    if (threadIdx.x == 0) bsum[blockIdx.x] = sm[0];
}

__global__ __launch_bounds__(256) void scan2(const int* __restrict__ bsum,
                                             int* __restrict__ boff,
                                             int* __restrict__ offs)
{
    __shared__ int sm[256];
    int t = threadIdx.x;
    int v = (t < NB) ? bsum[t] : 0;
    sm[t] = v;
    __syncthreads();
    for (int s = 1; s < 256; s <<= 1) {
        int x = sm[t];
        int y = (t >= s) ? sm[t - s] : 0;
        __syncthreads();
        sm[t] = x + y;
        __syncthreads();
    }
    if (t < NB) boff[t] = sm[t] - v;       // exclusive
    if (t == 255) offs[NN] = sm[255];      // total effective edge count
}

__global__ __launch_bounds__(256) void scan3(const int* __restrict__ deg,
                                             const int* __restrict__ boff,
                                             int* __restrict__ offs,
                                             int* __restrict__ cur)
{
    __shared__ int sm[256];
    int i = blockIdx.x * 256 + threadIdx.x;
    int t = threadIdx.x;
    int v = (i < NN) ? deg[i] : 0;
    sm[t] = v;
    __syncthreads();
    for (int s = 1; s < 256; s <<= 1) {
        int x = sm[t];
        int y = (t >= s) ? sm[t - s] : 0;
        __syncthreads();
        sm[t] = x + y;
        __syncthreads();
    }
    int excl = sm[t] - v + boff[blockIdx.x];
    if (i < NN) { offs[i] = excl; cur[i] = excl; }
}

__global__ __launch_bounds__(256) void fill_edges(const int* __restrict__ src,
                                                  const int* __restrict__ dst,
                                                  const int* __restrict__ pos,
                                                  const float* __restrict__ dist,
                                                  int* __restrict__ cur,
                                                  int2* __restrict__ elist)
{
    int e = blockIdx.x * 256 + threadIdx.x;
    if (e >= EE) return;
    int p = pos[e];
    if (p == 3) return;
    int slot = atomicAdd(&cur[dst[e]], 1);
    elist[slot] = make_int2(src[e] | (p << 16), __float_as_int(dist[e]));
}

// ---------------------------------------------------------------------------
// Gather-aggregation: one wave per dst node. No f32 atomics, no agg memset.
// agg layout: [3][NN][128] f32 — fully written (zeros where no edges).
// ---------------------------------------------------------------------------
__global__ __launch_bounds__(256) void gather_agg(const float* __restrict__ h,
                                                  const int2* __restrict__ elist,
                                                  const int* __restrict__ offs,
                                                  float* __restrict__ agg)
{
    int node = (blockIdx.x * 256 + threadIdx.x) >> 6;
    if (node >= NN) return;
    int lane = threadIdx.x & 63;
    int beg = offs[node], end = offs[node + 1];

    float2 a0 = {0.f, 0.f}, a1 = {0.f, 0.f}, a2 = {0.f, 0.f};
    for (int e = beg; e < end; ++e) {
        int2 m = elist[e];                 // same addr across wave -> broadcast
        int   s = m.x & 0xFFFF;
        int   p = m.x >> 16;               // wave-uniform branch below
        float w = __int_as_float(m.y);
        float2 v = ((const float2*)(h + (size_t)s * D))[lane];  // 512B/wave
        if (p == 0)      { a0.x = fmaf(v.x, w, a0.x); a0.y = fmaf(v.y, w, a0.y); }
        else if (p == 1) { a1.x = fmaf(v.x, w, a1.x); a1.y = fmaf(v.y, w, a1.y); }
        else             { a2.x = fmaf(v.x, w, a2.x); a2.y = fmaf(v.y, w, a2.y); }
    }
    size_t o = (size_t)node * D + lane * 2;
    *(float2*)(agg + o)                      = a0;
    *(float2*)(agg + (size_t)NN * D + o)     = a1;
    *(float2*)(agg + (size_t)2 * NN * D + o) = a2;
}

// ---------------------------------------------------------------------------
// Fused GEMM (M=NN, N=128, K=512) + bias + LayerNorm + ReLU.
// Block: 256 threads, tile 64 rows x 128 cols, Kc = 64.
// Thread (r = t/16, c = t%16) owns rows {r+16i}, cols {c*4..+3, 64+c*4..+3}:
// Ws float4 reads hit 16 consecutive addresses -> 2-way bank alias (free).
// ---------------------------------------------------------------------------
__global__ __launch_bounds__(256) void gemm_ln(const float* __restrict__ h,
                                               const float* __restrict__ agg,
                                               const float* __restrict__ Wt,
                                               const float* __restrict__ bias,
                                               const float* __restrict__ gamma,
                                               const float* __restrict__ beta,
                                               float* __restrict__ out)
{
    __shared__ float Xs[64][68];
    __shared__ float Ws[64][128];
    const int t = threadIdx.x;
    const int r = t >> 4;
    const int c = t & 15;
    const int row0 = blockIdx.x * 64;

    float acc[4][8];
#pragma unroll
    for (int i = 0; i < 4; ++i)
#pragma unroll
        for (int j = 0; j < 8; ++j) acc[i][j] = 0.f;

    const float* xseg[4];
    xseg[0] = h;                           // k   0..127
    xseg[1] = agg;                         // k 128..255 (r, t folded in)
    xseg[2] = agg + (size_t)NN * D;        // k 256..383 (bt)
    xseg[3] = agg + (size_t)2 * NN * D;    // k 384..511 (l)

    for (int kc = 0; kc < 8; ++kc) {
        const int k0 = kc * 64;
        const float* X = xseg[k0 >> 7];
        const int koff = k0 & 127;
#pragma unroll
        for (int i = 0; i < 16; ++i) {
            int idx = t + 256 * i;
            int m = idx >> 6, kk = idx & 63;
            int row = row0 + m;
            Xs[m][kk] = (row < NN) ? X[(size_t)row * D + koff + kk] : 0.f;
        }
#pragma unroll
        for (int i = 0; i < 32; ++i) {
            int idx = t + 256 * i;
            int kk = idx >> 7, o = idx & 127;
            Ws[kk][o] = Wt[(size_t)(k0 + kk) * D + o];
        }
        __syncthreads();
#pragma unroll
        for (int k = 0; k < 64; k += 4) {
            float4 xv[4];
#pragma unroll
            for (int i = 0; i < 4; ++i)
                xv[i] = *(const float4*)&Xs[r + 16 * i][k];
#pragma unroll
            for (int kk = 0; kk < 4; ++kk) {
                float4 w0 = *(const float4*)&Ws[k + kk][c * 4];
                float4 w1 = *(const float4*)&Ws[k + kk][64 + c * 4];
#pragma unroll
                for (int i = 0; i < 4; ++i) {
                    float x = ((const float*)&xv[i])[kk];
                    acc[i][0] = fmaf(x, w0.x, acc[i][0]);
                    acc[i][1] = fmaf(x, w0.y, acc[i][1]);
                    acc[i][2] = fmaf(x, w0.z, acc[i][2]);
                    acc[i][3] = fmaf(x, w0.w, acc[i][3]);
                    acc[i][4] = fmaf(x, w1.x, acc[i][4]);
                    acc[i][5] = fmaf(x, w1.y, acc[i][5]);
                    acc[i][6] = fmaf(x, w1.z, acc[i][6]);
                    acc[i][7] = fmaf(x, w1.w, acc[i][7]);
                }
            }
        }
        __syncthreads();
    }

    // epilogue: +bias, LayerNorm over 128 cols (16-lane shfl reduce), ReLU
    float bb[8], gg[8], be[8];
    *(float4*)&bb[0] = *(const float4*)&bias[c * 4];
    *(float4*)&bb[4] = *(const float4*)&bias[64 + c * 4];
    *(float4*)&gg[0] = *(const float4*)&gamma[c * 4];
    *(float4*)&gg[4] = *(const float4*)&gamma[64 + c * 4];
    *(float4*)&be[0] = *(const float4*)&beta[c * 4];
    *(float4*)&be[4] = *(const float4*)&beta[64 + c * 4];

#pragma unroll
    for (int i = 0; i < 4; ++i) {
        float s = 0.f, ss = 0.f;
#pragma unroll
        for (int j = 0; j < 8; ++j) {
            float z = acc[i][j] + bb[j];
            acc[i][j] = z;
            s += z;
            ss += z * z;
        }
        // 16 consecutive lanes (same r) hold the 128 cols of this row
#pragma unroll
        for (int m = 1; m < 16; m <<= 1) {
            s  += __shfl_xor(s, m, 64);
            ss += __shfl_xor(ss, m, 64);
        }
        float mu  = s * (1.f / 128.f);
        float var = ss * (1.f / 128.f) - mu * mu;
        float rs  = rsqrtf(var + 1e-5f);
        int row = row0 + r + 16 * i;
        if (row < NN) {
            float o8[8];
#pragma unroll
            for (int j = 0; j < 8; ++j) {
                float v = (acc[i][j] - mu) * rs * gg[j] + be[j];
                o8[j] = v > 0.f ? v : 0.f;
            }
            *(float4*)&out[(size_t)row * D + c * 4]      = *(float4*)&o8[0];
            *(float4*)&out[(size_t)row * D + 64 + c * 4] = *(float4*)&o8[4];
        }
    }
}

// ---------------------------------------------------------------------------
extern "C" void kernel_launch(void* const* d_in, const int* in_sizes, int n_in,
                              void* d_out, int out_size, void* d_ws, size_t ws_size,
                              hipStream_t stream)
{
    const float* h     = (const float*)d_in[0];
    const float* dist  = (const float*)d_in[1];
    const float* W     = (const float*)d_in[2];
    const float* bias  = (const float*)d_in[3];
    const float* gamma = (const float*)d_in[4];
    const float* beta  = (const float*)d_in[5];
    const int*   src   = (const int*)d_in[6];
    const int*   dst   = (const int*)d_in[7];
    const int*   pos   = (const int*)d_in[8];

    // workspace layout
    float* agg  = (float*)d_ws;                        // [3][NN][128] = 76.8 MB
    float* Wt   = agg + (size_t)3 * NN * D;            // [512][128]   = 256 KB
    int*   deg  = (int*)(Wt + 512 * 128);              // [NN]
    int*   offs = deg + NN;                            // [NN+1]
    int*   cur  = offs + NN + 1;                       // [NN]
    int*   bsum = cur + NN;                            // [256]
    int*   boff = bsum + 256;                          // [256]
    int2*  elist = (int2*)(((uintptr_t)(boff + 256) + 15) & ~(uintptr_t)15);

    hipMemsetAsync(deg, 0, NN * sizeof(int), stream);

    prep_w<<<(512 * 128) / 256, 256, 0, stream>>>(W, Wt);
    count_deg<<<(EE + 255) / 256, 256, 0, stream>>>(dst, pos, deg);
    scan1<<<NB, 256, 0, stream>>>(deg, bsum);
    scan2<<<1, 256, 0, stream>>>(bsum, boff, offs);
    scan3<<<NB, 256, 0, stream>>>(deg, boff, offs, cur);
    fill_edges<<<(EE + 255) / 256, 256, 0, stream>>>(src, dst, pos, dist, cur, elist);
    gather_agg<<<(NN * 64) / 256, 256, 0, stream>>>(h, elist, offs, agg);
    gemm_ln<<<(NN + 63) / 64, 256, 0, stream>>>(h, agg, Wt, bias, gamma, beta,
                                                (float*)d_out);
}

// Round 3
// 277.585 us; speedup vs baseline: 3.1046x; 1.7962x over previous
//
#include <hip/hip_runtime.h>
#include <math.h>
#include <stdint.h>

constexpr int NN = 50000;   // nodes
constexpr int EE = 800000;  // edges
constexpr int D  = 128;     // feature dim
constexpr int KK = 512;     // effective GEMM K (t folded into r)
constexpr int BM = 128;     // gemm row tile
constexpr int BK = 64;      // gemm k tile
constexpr int NPAD = 50048; // 391 * 128
constexpr int NB = (NN + 255) / 256;  // 196 scan blocks

typedef __attribute__((ext_vector_type(8)))  short bf16x8;
typedef __attribute__((ext_vector_type(16))) float f32x16;

__device__ inline unsigned short f2bf(float x) {
    unsigned u = __builtin_bit_cast(unsigned, x);
    unsigned r = (u + 0x7FFF + ((u >> 16) & 1)) >> 16;   // RNE
    return (unsigned short)r;
}
__device__ inline float bf2f(unsigned short b) {
    unsigned u = ((unsigned)b) << 16;
    return __builtin_bit_cast(float, u);
}

// ---------------------------------------------------------------------------
// h -> Xhi/Xlo rows, k-segment [0,128). X row layout: [h | p0 | p1 | p2], K=512.
// ---------------------------------------------------------------------------
__global__ __launch_bounds__(256) void h_split(const float* __restrict__ h,
                                               unsigned short* __restrict__ Xhi,
                                               unsigned short* __restrict__ Xlo)
{
    int idx = blockIdx.x * 256 + threadIdx.x;  // NN*32 threads, 4 elems each
    int n  = idx >> 5;
    int c4 = (idx & 31) * 4;
    float4 v = *(const float4*)(h + (size_t)n * D + c4);
    float vv[4] = {v.x, v.y, v.z, v.w};
    unsigned short hb[4], lb[4];
#pragma unroll
    for (int j = 0; j < 4; ++j) {
        hb[j] = f2bf(vv[j]);
        lb[j] = f2bf(vv[j] - bf2f(hb[j]));
    }
    size_t o = (size_t)n * KK + c4;
    *(uint2*)(Xhi + o) = make_uint2((unsigned)hb[0] | ((unsigned)hb[1] << 16),
                                    (unsigned)hb[2] | ((unsigned)hb[3] << 16));
    *(uint2*)(Xlo + o) = make_uint2((unsigned)lb[0] | ((unsigned)lb[1] << 16),
                                    (unsigned)lb[2] | ((unsigned)lb[3] << 16));
}

// ---------------------------------------------------------------------------
// W[128][640] -> Whi/Wlo[128 cols][512 k] (k-contig per out-col), t folded.
// ---------------------------------------------------------------------------
__global__ __launch_bounds__(256) void prep_w(const float* __restrict__ W,
                                              unsigned short* __restrict__ Whi,
                                              unsigned short* __restrict__ Wlo)
{
    int idx = blockIdx.x * 256 + threadIdx.x;  // 128*512
    int o = idx >> 9, k = idx & 511;
    float v = W[o * 640 + k];
    if (k >= 128 && k < 256) v += W[o * 640 + k + 384];
    unsigned short hb = f2bf(v);
    Whi[idx] = hb;
    Wlo[idx] = f2bf(v - bf2f(hb));
}

// ---------------------------------------------------------------------------
// CSR build (count -> scan -> fill), p==3 edges dropped.
// ---------------------------------------------------------------------------
__global__ __launch_bounds__(256) void count_deg(const int* __restrict__ dst,
                                                 const int* __restrict__ pos,
                                                 int* __restrict__ deg)
{
    int e = blockIdx.x * 256 + threadIdx.x;
    if (e >= EE) return;
    if (pos[e] == 3) return;
    atomicAdd(&deg[dst[e]], 1);
}

__global__ __launch_bounds__(256) void scan1(const int* __restrict__ deg,
                                             int* __restrict__ bsum)
{
    __shared__ int sm[256];
    int i = blockIdx.x * 256 + threadIdx.x;
    sm[threadIdx.x] = (i < NN) ? deg[i] : 0;
    __syncthreads();
    for (int s = 128; s > 0; s >>= 1) {
        if (threadIdx.x < s) sm[threadIdx.x] += sm[threadIdx.x + s];
        __syncthreads();
    }
    if (threadIdx.x == 0) bsum[blockIdx.x] = sm[0];
}

__global__ __launch_bounds__(256) void scan2(const int* __restrict__ bsum,
                                             int* __restrict__ boff,
                                             int* __restrict__ offs)
{
    __shared__ int sm[256];
    int t = threadIdx.x;
    int v = (t < NB) ? bsum[t] : 0;
    sm[t] = v;
    __syncthreads();
    for (int s = 1; s < 256; s <<= 1) {
        int x = sm[t];
        int y = (t >= s) ? sm[t - s] : 0;
        __syncthreads();
        sm[t] = x + y;
        __syncthreads();
    }
    if (t < NB) boff[t] = sm[t] - v;
    if (t == 255) offs[NN] = sm[255];
}

__global__ __launch_bounds__(256) void scan3(const int* __restrict__ deg,
                                             const int* __restrict__ boff,
                                             int* __restrict__ offs,
                                             int* __restrict__ cur)
{
    __shared__ int sm[256];
    int i = blockIdx.x * 256 + threadIdx.x;
    int t = threadIdx.x;
    int v = (i < NN) ? deg[i] : 0;
    sm[t] = v;
    __syncthreads();
    for (int s = 1; s < 256; s <<= 1) {
        int x = sm[t];
        int y = (t >= s) ? sm[t - s] : 0;
        __syncthreads();
        sm[t] = x + y;
        __syncthreads();
    }
    int excl = sm[t] - v + boff[blockIdx.x];
    if (i < NN) { offs[i] = excl; cur[i] = excl; }
}

__global__ __launch_bounds__(256) void fill_edges(const int* __restrict__ src,
                                                  const int* __restrict__ dst,
                                                  const int* __restrict__ pos,
                                                  const float* __restrict__ dist,
                                                  int* __restrict__ cur,
                                                  int2* __restrict__ elist)
{
    int e = blockIdx.x * 256 + threadIdx.x;
    if (e >= EE) return;
    int p = pos[e];
    if (p == 3) return;
    int slot = atomicAdd(&cur[dst[e]], 1);
    elist[slot] = make_int2(src[e] | (p << 16), __float_as_int(dist[e]));
}

// ---------------------------------------------------------------------------
// Gather-aggregation: one wave per dst node; accumulate f32, emit bf16 hi/lo
// into X rows at k-segments 128+p*128.
// ---------------------------------------------------------------------------
__global__ __launch_bounds__(256) void gather_agg(const float* __restrict__ h,
                                                  const int2* __restrict__ elist,
                                                  const int* __restrict__ offs,
                                                  unsigned short* __restrict__ Xhi,
                                                  unsigned short* __restrict__ Xlo)
{
    int node = (blockIdx.x * 256 + threadIdx.x) >> 6;
    if (node >= NN) return;
    int lane = threadIdx.x & 63;
    int beg = offs[node], end = offs[node + 1];

    float2 a0 = {0.f, 0.f}, a1 = {0.f, 0.f}, a2 = {0.f, 0.f};
#pragma unroll 2
    for (int e = beg; e < end; ++e) {
        int2 m = elist[e];                 // wave-uniform broadcast
        int   s = m.x & 0xFFFF;            // NN < 65536
        int   p = m.x >> 16;
        float w = __int_as_float(m.y);
        float2 v = ((const float2*)(h + (size_t)s * D))[lane];
        if (p == 0)      { a0.x = fmaf(v.x, w, a0.x); a0.y = fmaf(v.y, w, a0.y); }
        else if (p == 1) { a1.x = fmaf(v.x, w, a1.x); a1.y = fmaf(v.y, w, a1.y); }
        else             { a2.x = fmaf(v.x, w, a2.x); a2.y = fmaf(v.y, w, a2.y); }
    }

    size_t base = (size_t)node * KK + 128 + lane * 2;
    float2 as[3] = {a0, a1, a2};
#pragma unroll
    for (int p = 0; p < 3; ++p) {
        unsigned short h0 = f2bf(as[p].x), h1 = f2bf(as[p].y);
        unsigned short l0 = f2bf(as[p].x - bf2f(h0));
        unsigned short l1 = f2bf(as[p].y - bf2f(h1));
        *(unsigned*)(Xhi + base + p * 128) = (unsigned)h0 | ((unsigned)h1 << 16);
        *(unsigned*)(Xlo + base + p * 128) = (unsigned)l0 | ((unsigned)l1 << 16);
    }
}

// ---------------------------------------------------------------------------
// MFMA GEMM (M=NPAD, N=128, K=512) via 3-term bf16 hi/lo split + fused LN+ReLU.
// Block 256 thr (4 waves); tile 128x128; wave w owns rows (w&1)*64, cols (w>>1)*64.
// LDS: Ahi/Alo/Bhi/Blo [128][64] bf16, XOR-swizzled: kslot' = kslot ^ (row&7)
// (G4 fix for 128B-row ds_read_b128 conflicts; swizzle on write AND read).
// 32x32x16 frags: A lane l: A[l&31][(l>>5)*8+j]; B lane l: B[(l>>5)*8+j][l&31];
// C: col=lane&31, row=(reg&3)+8*(reg>>2)+4*(lane>>5)  [m74/m101 verified].
// ---------------------------------------------------------------------------
__global__ __launch_bounds__(256, 2) void gemm_mfma(
    const unsigned short* __restrict__ Xhi, const unsigned short* __restrict__ Xlo,
    const unsigned short* __restrict__ Whi, const unsigned short* __restrict__ Wlo,
    const float* __restrict__ bias, const float* __restrict__ gamma,
    const float* __restrict__ beta, float* __restrict__ out)
{
    __shared__ __align__(16) short lds[4 * BM * BK];   // 64 KB
    short* SAh = lds;
    short* SAl = lds + BM * BK;
    short* SBh = lds + 2 * BM * BK;
    short* SBl = lds + 3 * BM * BK;

    const int t = threadIdx.x;
    const int l = t & 63;
    const int w = t >> 6;
    const int wr = (w & 1) * 64;
    const int wc = (w >> 1) * 64;
    const int row0 = blockIdx.x * BM;
    const int ln = l & 31;
    const int hs = l >> 5;

    f32x16 acc[2][2];
#pragma unroll
    for (int a = 0; a < 2; ++a)
#pragma unroll
        for (int b = 0; b < 2; ++b)
#pragma unroll
            for (int i = 0; i < 16; ++i) acc[a][b][i] = 0.f;

    for (int ks = 0; ks < 8; ++ks) {
        const int k0 = ks * BK;
        // stage 4 tiles; linear global reads, swizzled ds_write_b128
#pragma unroll
        for (int pass = 0; pass < 4; ++pass) {
            int idx = t + 256 * pass;          // 0..1023
            int row = idx >> 3;                // 0..127
            int kslot = idx & 7;
            int lof = row * 64 + ((kslot ^ (row & 7)) * 8);
            size_t ga = (size_t)(row0 + row) * KK + k0 + kslot * 8;
            size_t gb = (size_t)row * KK + k0 + kslot * 8;
            *(bf16x8*)(SAh + lof) = *(const bf16x8*)(Xhi + ga);
            *(bf16x8*)(SAl + lof) = *(const bf16x8*)(Xlo + ga);
            *(bf16x8*)(SBh + lof) = *(const bf16x8*)(Whi + gb);
            *(bf16x8*)(SBl + lof) = *(const bf16x8*)(Wlo + gb);
        }
        __syncthreads();
#pragma unroll
        for (int kk = 0; kk < 4; ++kk) {
            const int ksl = kk * 2 + hs;
            bf16x8 ah[2], al[2], bh[2], bl[2];
#pragma unroll
            for (int rb = 0; rb < 2; ++rb) {
                int row = wr + rb * 32 + ln;
                int off = row * 64 + ((ksl ^ (row & 7)) * 8);
                ah[rb] = *(const bf16x8*)(SAh + off);
                al[rb] = *(const bf16x8*)(SAl + off);
            }
#pragma unroll
            for (int cb = 0; cb < 2; ++cb) {
                int col = wc + cb * 32 + ln;
                int off = col * 64 + ((ksl ^ (col & 7)) * 8);
                bh[cb] = *(const bf16x8*)(SBh + off);
                bl[cb] = *(const bf16x8*)(SBl + off);
            }
#pragma unroll
            for (int rb = 0; rb < 2; ++rb)
#pragma unroll
                for (int cb = 0; cb < 2; ++cb) {
                    acc[rb][cb] = __builtin_amdgcn_mfma_f32_32x32x16_bf16(
                        ah[rb], bh[cb], acc[rb][cb], 0, 0, 0);
                    acc[rb][cb] = __builtin_amdgcn_mfma_f32_32x32x16_bf16(
                        ah[rb], bl[cb], acc[rb][cb], 0, 0, 0);
                    acc[rb][cb] = __builtin_amdgcn_mfma_f32_32x32x16_bf16(
                        al[rb], bh[cb], acc[rb][cb], 0, 0, 0);
                }
        }
        __syncthreads();
    }

    // ---- fused bias + LayerNorm + ReLU epilogue ----
    float* part = (float*)lds;  // [2 col-half][128 row][2] f32, reuse LDS
    float bias_c[2] = {bias[wc + ln], bias[wc + 32 + ln]};

#pragma unroll
    for (int rb = 0; rb < 2; ++rb)
#pragma unroll
        for (int reg = 0; reg < 16; ++reg) {
            float z0 = acc[rb][0][reg] + bias_c[0];
            float z1 = acc[rb][1][reg] + bias_c[1];
            acc[rb][0][reg] = z0;
            acc[rb][1][reg] = z1;
            float s = z0 + z1, ss = z0 * z0 + z1 * z1;
#pragma unroll
            for (int m = 1; m < 32; m <<= 1) {
                s  += __shfl_xor(s, m, 64);
                ss += __shfl_xor(ss, m, 64);
            }
            int rl = wr + rb * 32 + (reg & 3) + 8 * (reg >> 2) + 4 * hs;
            if (ln == 0) {
                part[(w >> 1) * 256 + rl * 2]     = s;
                part[(w >> 1) * 256 + rl * 2 + 1] = ss;
            }
        }
    __syncthreads();

    float g_c[2]  = {gamma[wc + ln], gamma[wc + 32 + ln]};
    float be_c[2] = {beta[wc + ln],  beta[wc + 32 + ln]};
#pragma unroll
    for (int rb = 0; rb < 2; ++rb)
#pragma unroll
        for (int reg = 0; reg < 16; ++reg) {
            int rl = wr + rb * 32 + (reg & 3) + 8 * (reg >> 2) + 4 * hs;
            float s  = part[rl * 2]     + part[256 + rl * 2];
            float ss = part[rl * 2 + 1] + part[256 + rl * 2 + 1];
            float mu  = s * (1.f / 128.f);
            float var = ss * (1.f / 128.f) - mu * mu;
            float rs  = rsqrtf(var + 1e-5f);
            int grow = row0 + rl;
            if (grow < NN) {
                float v0 = (acc[rb][0][reg] - mu) * rs * g_c[0] + be_c[0];
                float v1 = (acc[rb][1][reg] - mu) * rs * g_c[1] + be_c[1];
                out[(size_t)grow * D + wc + ln]      = v0 > 0.f ? v0 : 0.f;
                out[(size_t)grow * D + wc + 32 + ln] = v1 > 0.f ? v1 : 0.f;
            }
        }
}

// ---------------------------------------------------------------------------
extern "C" void kernel_launch(void* const* d_in, const int* in_sizes, int n_in,
                              void* d_out, int out_size, void* d_ws, size_t ws_size,
                              hipStream_t stream)
{
    const float* h     = (const float*)d_in[0];
    const float* dist  = (const float*)d_in[1];
    const float* W     = (const float*)d_in[2];
    const float* bias  = (const float*)d_in[3];
    const float* gamma = (const float*)d_in[4];
    const float* beta  = (const float*)d_in[5];
    const int*   src   = (const int*)d_in[6];
    const int*   dst   = (const int*)d_in[7];
    const int*   pos   = (const int*)d_in[8];

    // workspace layout
    unsigned short* Xhi = (unsigned short*)d_ws;            // [NPAD][512] bf16
    unsigned short* Xlo = Xhi + (size_t)NPAD * KK;          // [NPAD][512] bf16
    unsigned short* Whi = Xlo + (size_t)NPAD * KK;          // [128][512] bf16
    unsigned short* Wlo = Whi + 128 * KK;                   // [128][512] bf16
    int* deg  = (int*)(Wlo + 128 * KK);                     // [NN]
    int* offs = deg + NN;                                   // [NN+1]
    int* cur  = offs + NN + 1;                              // [NN]
    int* bsum = cur + NN;                                   // [256]
    int* boff = bsum + 256;                                 // [256]
    int2* elist = (int2*)(((uintptr_t)(boff + 256) + 15) & ~(uintptr_t)15);

    hipMemsetAsync(deg, 0, NN * sizeof(int), stream);

    h_split<<<(NN * 32) / 256, 256, 0, stream>>>(h, Xhi, Xlo);
    prep_w<<<(128 * KK) / 256, 256, 0, stream>>>(W, Whi, Wlo);
    count_deg<<<(EE + 255) / 256, 256, 0, stream>>>(dst, pos, deg);
    scan1<<<NB, 256, 0, stream>>>(deg, bsum);
    scan2<<<1, 256, 0, stream>>>(bsum, boff, offs);
    scan3<<<NB, 256, 0, stream>>>(deg, boff, offs, cur);
    fill_edges<<<(EE + 255) / 256, 256, 0, stream>>>(src, dst, pos, dist, cur, elist);
    gather_agg<<<(NN * 64) / 256, 256, 0, stream>>>(h, elist, offs, Xhi, Xlo);
    gemm_mfma<<<NPAD / BM, 256, 0, stream>>>(Xhi, Xlo, Whi, Wlo, bias, gamma, beta,
                                             (float*)d_out);
}

// Round 4
// 255.335 us; speedup vs baseline: 3.3751x; 1.0871x over previous
//
#include <hip/hip_runtime.h>
#include <math.h>
#include <stdint.h>

constexpr int NN = 50000;   // nodes
constexpr int EE = 800000;  // edges
constexpr int D  = 128;     // feature dim
constexpr int KK = 512;     // effective GEMM K (t folded into r)
constexpr int KA = 384;     // agg-only K segments (3 * 128)
constexpr int BM = 128;     // gemm row tile
constexpr int BK = 64;      // gemm k tile
constexpr int NPAD = 50048; // 391 * 128
constexpr int NB = (NN + 255) / 256;  // 196 scan blocks

typedef __attribute__((ext_vector_type(8)))  short bf16x8;
typedef __attribute__((ext_vector_type(16))) float f32x16;

__device__ inline unsigned short f2bf(float x) {
    unsigned u = __builtin_bit_cast(unsigned, x);
    unsigned r = (u + 0x7FFF + ((u >> 16) & 1)) >> 16;   // RNE
    return (unsigned short)r;
}
__device__ inline float bf2f(unsigned short b) {
    unsigned u = ((unsigned)b) << 16;
    return __builtin_bit_cast(float, u);
}

// ---------------------------------------------------------------------------
// W[128][640] -> Whi/Wlo[128 cols][512 k] (k-contig per out-col), t folded.
// ---------------------------------------------------------------------------
__global__ __launch_bounds__(256) void prep_w(const float* __restrict__ W,
                                              unsigned short* __restrict__ Whi,
                                              unsigned short* __restrict__ Wlo)
{
    int idx = blockIdx.x * 256 + threadIdx.x;  // 128*512
    int o = idx >> 9, k = idx & 511;
    float v = W[o * 640 + k];
    if (k >= 128 && k < 256) v += W[o * 640 + k + 384];
    unsigned short hb = f2bf(v);
    Whi[idx] = hb;
    Wlo[idx] = f2bf(v - bf2f(hb));
}

// ---------------------------------------------------------------------------
// CSR build (count -> scan -> fill), p==3 edges dropped.
// ---------------------------------------------------------------------------
__global__ __launch_bounds__(256) void count_deg(const int* __restrict__ dst,
                                                 const int* __restrict__ pos,
                                                 int* __restrict__ deg)
{
    int e = blockIdx.x * 256 + threadIdx.x;
    if (e >= EE) return;
    if (pos[e] == 3) return;
    atomicAdd(&deg[dst[e]], 1);
}

__global__ __launch_bounds__(256) void scan1(const int* __restrict__ deg,
                                             int* __restrict__ bsum)
{
    __shared__ int sm[256];
    int i = blockIdx.x * 256 + threadIdx.x;
    sm[threadIdx.x] = (i < NN) ? deg[i] : 0;
    __syncthreads();
    for (int s = 128; s > 0; s >>= 1) {
        if (threadIdx.x < s) sm[threadIdx.x] += sm[threadIdx.x + s];
        __syncthreads();
    }
    if (threadIdx.x == 0) bsum[blockIdx.x] = sm[0];
}

__global__ __launch_bounds__(256) void scan2(const int* __restrict__ bsum,
                                             int* __restrict__ boff,
                                             int* __restrict__ offs)
{
    __shared__ int sm[256];
    int t = threadIdx.x;
    int v = (t < NB) ? bsum[t] : 0;
    sm[t] = v;
    __syncthreads();
    for (int s = 1; s < 256; s <<= 1) {
        int x = sm[t];
        int y = (t >= s) ? sm[t - s] : 0;
        __syncthreads();
        sm[t] = x + y;
        __syncthreads();
    }
    if (t < NB) boff[t] = sm[t] - v;
    if (t == 255) offs[NN] = sm[255];
}

__global__ __launch_bounds__(256) void scan3(const int* __restrict__ deg,
                                             const int* __restrict__ boff,
                                             int* __restrict__ offs,
                                             int* __restrict__ cur)
{
    __shared__ int sm[256];
    int i = blockIdx.x * 256 + threadIdx.x;
    int t = threadIdx.x;
    int v = (i < NN) ? deg[i] : 0;
    sm[t] = v;
    __syncthreads();
    for (int s = 1; s < 256; s <<= 1) {
        int x = sm[t];
        int y = (t >= s) ? sm[t - s] : 0;
        __syncthreads();
        sm[t] = x + y;
        __syncthreads();
    }
    int excl = sm[t] - v + boff[blockIdx.x];
    if (i < NN) { offs[i] = excl; cur[i] = excl; }
}

__global__ __launch_bounds__(256) void fill_edges(const int* __restrict__ src,
                                                  const int* __restrict__ dst,
                                                  const int* __restrict__ pos,
                                                  const float* __restrict__ dist,
                                                  int* __restrict__ cur,
                                                  int2* __restrict__ elist)
{
    int e = blockIdx.x * 256 + threadIdx.x;
    if (e >= EE) return;
    int p = pos[e];
    if (p == 3) return;
    int slot = atomicAdd(&cur[dst[e]], 1);
    elist[slot] = make_int2(src[e] | (p << 16), __float_as_int(dist[e]));
}

// ---------------------------------------------------------------------------
// Gather-aggregation: one wave per dst node. Edge metas preloaded lane-parallel
// (one 8B load covers 64 edges), broadcast via __shfl; h gathers issued in
// chunks of 4 so 4 x 512B loads are in flight. Predicated FMA (no divergence).
// Output: bf16 hi/lo into Xagg rows [node][KA=384], segment p*128.
// ---------------------------------------------------------------------------
__global__ __launch_bounds__(256) void gather_agg(const float* __restrict__ h,
                                                  const int2* __restrict__ elist,
                                                  const int* __restrict__ offs,
                                                  unsigned short* __restrict__ Xhi,
                                                  unsigned short* __restrict__ Xlo)
{
    int node = (blockIdx.x * 256 + threadIdx.x) >> 6;
    if (node >= NN) return;
    int lane = threadIdx.x & 63;
    int beg = offs[node], end = offs[node + 1];

    float2 a0 = {0.f, 0.f}, a1 = {0.f, 0.f}, a2 = {0.f, 0.f};

    for (int base = beg; base < end; base += 64) {
        int n = end - base;
        if (n > 64) n = 64;
        int2 mreg = (lane < n) ? elist[base + lane] : make_int2(0, 0);

        int e = 0;
        for (; e + 4 <= n; e += 4) {
            float2 v[4];
            float  wq[4];
            int    pq[4];
#pragma unroll
            for (int j = 0; j < 4; ++j) {
                int mx = __shfl(mreg.x, e + j);
                int my = __shfl(mreg.y, e + j);
                pq[j] = mx >> 16;
                wq[j] = __int_as_float(my);
                v[j]  = ((const float2*)(h + (size_t)(mx & 0xFFFF) * D))[lane];
            }
#pragma unroll
            for (int j = 0; j < 4; ++j) {
                float w0 = (pq[j] == 0) ? wq[j] : 0.f;
                float w1 = (pq[j] == 1) ? wq[j] : 0.f;
                float w2 = (pq[j] == 2) ? wq[j] : 0.f;
                a0.x = fmaf(v[j].x, w0, a0.x); a0.y = fmaf(v[j].y, w0, a0.y);
                a1.x = fmaf(v[j].x, w1, a1.x); a1.y = fmaf(v[j].y, w1, a1.y);
                a2.x = fmaf(v[j].x, w2, a2.x); a2.y = fmaf(v[j].y, w2, a2.y);
            }
        }
        for (; e < n; ++e) {
            int mx = __shfl(mreg.x, e);
            int my = __shfl(mreg.y, e);
            float w = __int_as_float(my);
            float2 v = ((const float2*)(h + (size_t)(mx & 0xFFFF) * D))[lane];
            float w0 = ((mx >> 16) == 0) ? w : 0.f;
            float w1 = ((mx >> 16) == 1) ? w : 0.f;
            float w2 = ((mx >> 16) == 2) ? w : 0.f;
            a0.x = fmaf(v.x, w0, a0.x); a0.y = fmaf(v.y, w0, a0.y);
            a1.x = fmaf(v.x, w1, a1.x); a1.y = fmaf(v.y, w1, a1.y);
            a2.x = fmaf(v.x, w2, a2.x); a2.y = fmaf(v.y, w2, a2.y);
        }
    }

    size_t base = (size_t)node * KA + lane * 2;
    float2 as[3] = {a0, a1, a2};
#pragma unroll
    for (int p = 0; p < 3; ++p) {
        unsigned short h0 = f2bf(as[p].x), h1 = f2bf(as[p].y);
        unsigned short l0 = f2bf(as[p].x - bf2f(h0));
        unsigned short l1 = f2bf(as[p].y - bf2f(h1));
        *(unsigned*)(Xhi + base + p * 128) = (unsigned)h0 | ((unsigned)h1 << 16);
        *(unsigned*)(Xlo + base + p * 128) = (unsigned)l0 | ((unsigned)l1 << 16);
    }
}

// ---------------------------------------------------------------------------
// MFMA GEMM (M=NPAD, N=128, K=512) via 3-term bf16 hi/lo split + fused LN+ReLU.
// k-tiles 0,1 read h f32 directly and convert during staging (no h_split,
// no X[0:128) traffic); k-tiles 2..7 read Xagg hi/lo (stride KA=384).
// LDS XOR swizzle kslot^=(row&7) on write AND read (reg-staged, rule #21 ok).
// 32x32x16 frags; C: col=lane&31, row=(reg&3)+8*(reg>>2)+4*(lane>>5).
// ---------------------------------------------------------------------------
__global__ __launch_bounds__(256, 2) void gemm_mfma(
    const float* __restrict__ h,
    const unsigned short* __restrict__ Xhi, const unsigned short* __restrict__ Xlo,
    const unsigned short* __restrict__ Whi, const unsigned short* __restrict__ Wlo,
    const float* __restrict__ bias, const float* __restrict__ gamma,
    const float* __restrict__ beta, float* __restrict__ out)
{
    __shared__ __align__(16) short lds[4 * BM * BK];   // 64 KB
    short* SAh = lds;
    short* SAl = lds + BM * BK;
    short* SBh = lds + 2 * BM * BK;
    short* SBl = lds + 3 * BM * BK;

    const int t = threadIdx.x;
    const int l = t & 63;
    const int w = t >> 6;
    const int wr = (w & 1) * 64;
    const int wc = (w >> 1) * 64;
    const int row0 = blockIdx.x * BM;
    const int ln = l & 31;
    const int hs = l >> 5;

    f32x16 acc[2][2];
#pragma unroll
    for (int a = 0; a < 2; ++a)
#pragma unroll
        for (int b = 0; b < 2; ++b)
#pragma unroll
            for (int i = 0; i < 16; ++i) acc[a][b][i] = 0.f;

    for (int ks = 0; ks < 8; ++ks) {
        const int k0 = ks * BK;
#pragma unroll
        for (int pass = 0; pass < 4; ++pass) {
            int idx = t + 256 * pass;          // 0..1023
            int row = idx >> 3;                // 0..127
            int kslot = idx & 7;
            int lof = row * 64 + ((kslot ^ (row & 7)) * 8);

            // ---- A tile ----
            if (ks < 2) {
                // from h f32, convert to hi/lo during staging
                int grow = row0 + row;
                float ff[8];
                if (grow < NN) {
                    const float* hp = h + (size_t)grow * D + k0 + kslot * 8;
                    float4 f0 = *(const float4*)hp;
                    float4 f1 = *(const float4*)(hp + 4);
                    ff[0] = f0.x; ff[1] = f0.y; ff[2] = f0.z; ff[3] = f0.w;
                    ff[4] = f1.x; ff[5] = f1.y; ff[6] = f1.z; ff[7] = f1.w;
                } else {
#pragma unroll
                    for (int j = 0; j < 8; ++j) ff[j] = 0.f;
                }
                short ah8[8], al8[8];
#pragma unroll
                for (int j = 0; j < 8; ++j) {
                    unsigned short hb = f2bf(ff[j]);
                    ah8[j] = (short)hb;
                    al8[j] = (short)f2bf(ff[j] - bf2f(hb));
                }
                *(bf16x8*)(SAh + lof) = *(bf16x8*)ah8;
                *(bf16x8*)(SAl + lof) = *(bf16x8*)al8;
            } else {
                size_t ga = (size_t)(row0 + row) * KA + (k0 - 128) + kslot * 8;
                *(bf16x8*)(SAh + lof) = *(const bf16x8*)(Xhi + ga);
                *(bf16x8*)(SAl + lof) = *(const bf16x8*)(Xlo + ga);
            }
            // ---- B tile (W, stride 512, full K) ----
            size_t gb = (size_t)row * KK + k0 + kslot * 8;
            *(bf16x8*)(SBh + lof) = *(const bf16x8*)(Whi + gb);
            *(bf16x8*)(SBl + lof) = *(const bf16x8*)(Wlo + gb);
        }
        __syncthreads();
#pragma unroll
        for (int kk = 0; kk < 4; ++kk) {
            const int ksl = kk * 2 + hs;
            bf16x8 ah[2], al[2], bh[2], bl[2];
#pragma unroll
            for (int rb = 0; rb < 2; ++rb) {
                int row = wr + rb * 32 + ln;
                int off = row * 64 + ((ksl ^ (row & 7)) * 8);
                ah[rb] = *(const bf16x8*)(SAh + off);
                al[rb] = *(const bf16x8*)(SAl + off);
            }
#pragma unroll
            for (int cb = 0; cb < 2; ++cb) {
                int col = wc + cb * 32 + ln;
                int off = col * 64 + ((ksl ^ (col & 7)) * 8);
                bh[cb] = *(const bf16x8*)(SBh + off);
                bl[cb] = *(const bf16x8*)(SBl + off);
            }
#pragma unroll
            for (int rb = 0; rb < 2; ++rb)
#pragma unroll
                for (int cb = 0; cb < 2; ++cb) {
                    acc[rb][cb] = __builtin_amdgcn_mfma_f32_32x32x16_bf16(
                        ah[rb], bh[cb], acc[rb][cb], 0, 0, 0);
                    acc[rb][cb] = __builtin_amdgcn_mfma_f32_32x32x16_bf16(
                        ah[rb], bl[cb], acc[rb][cb], 0, 0, 0);
                    acc[rb][cb] = __builtin_amdgcn_mfma_f32_32x32x16_bf16(
                        al[rb], bh[cb], acc[rb][cb], 0, 0, 0);
                }
        }
        __syncthreads();
    }

    // ---- fused bias + LayerNorm + ReLU epilogue ----
    float* part = (float*)lds;  // [2 col-half][128 row][2] f32, reuse LDS
    float bias_c[2] = {bias[wc + ln], bias[wc + 32 + ln]};

#pragma unroll
    for (int rb = 0; rb < 2; ++rb)
#pragma unroll
        for (int reg = 0; reg < 16; ++reg) {
            float z0 = acc[rb][0][reg] + bias_c[0];
            float z1 = acc[rb][1][reg] + bias_c[1];
            acc[rb][0][reg] = z0;
            acc[rb][1][reg] = z1;
            float s = z0 + z1, ss = z0 * z0 + z1 * z1;
#pragma unroll
            for (int m = 1; m < 32; m <<= 1) {
                s  += __shfl_xor(s, m, 64);
                ss += __shfl_xor(ss, m, 64);
            }
            int rl = wr + rb * 32 + (reg & 3) + 8 * (reg >> 2) + 4 * hs;
            if (ln == 0) {
                part[(w >> 1) * 256 + rl * 2]     = s;
                part[(w >> 1) * 256 + rl * 2 + 1] = ss;
            }
        }
    __syncthreads();

    float g_c[2]  = {gamma[wc + ln], gamma[wc + 32 + ln]};
    float be_c[2] = {beta[wc + ln],  beta[wc + 32 + ln]};
#pragma unroll
    for (int rb = 0; rb < 2; ++rb)
#pragma unroll
        for (int reg = 0; reg < 16; ++reg) {
            int rl = wr + rb * 32 + (reg & 3) + 8 * (reg >> 2) + 4 * hs;
            float s  = part[rl * 2]     + part[256 + rl * 2];
            float ss = part[rl * 2 + 1] + part[256 + rl * 2 + 1];
            float mu  = s * (1.f / 128.f);
            float var = ss * (1.f / 128.f) - mu * mu;
            float rs  = rsqrtf(var + 1e-5f);
            int grow = row0 + rl;
            if (grow < NN) {
                float v0 = (acc[rb][0][reg] - mu) * rs * g_c[0] + be_c[0];
                float v1 = (acc[rb][1][reg] - mu) * rs * g_c[1] + be_c[1];
                out[(size_t)grow * D + wc + ln]      = v0 > 0.f ? v0 : 0.f;
                out[(size_t)grow * D + wc + 32 + ln] = v1 > 0.f ? v1 : 0.f;
            }
        }
}

// ---------------------------------------------------------------------------
extern "C" void kernel_launch(void* const* d_in, const int* in_sizes, int n_in,
                              void* d_out, int out_size, void* d_ws, size_t ws_size,
                              hipStream_t stream)
{
    const float* h     = (const float*)d_in[0];
    const float* dist  = (const float*)d_in[1];
    const float* W     = (const float*)d_in[2];
    const float* bias  = (const float*)d_in[3];
    const float* gamma = (const float*)d_in[4];
    const float* beta  = (const float*)d_in[5];
    const int*   src   = (const int*)d_in[6];
    const int*   dst   = (const int*)d_in[7];
    const int*   pos   = (const int*)d_in[8];

    // workspace layout
    unsigned short* Xhi = (unsigned short*)d_ws;            // [NPAD][384] bf16
    unsigned short* Xlo = Xhi + (size_t)NPAD * KA;          // [NPAD][384] bf16
    unsigned short* Whi = Xlo + (size_t)NPAD * KA;          // [128][512] bf16
    unsigned short* Wlo = Whi + 128 * KK;                   // [128][512] bf16
    int* deg  = (int*)(Wlo + 128 * KK);                     // [NN]
    int* offs = deg + NN;                                   // [NN+1]
    int* cur  = offs + NN + 1;                              // [NN]
    int* bsum = cur + NN;                                   // [256]
    int* boff = bsum + 256;                                 // [256]
    int2* elist = (int2*)(((uintptr_t)(boff + 256) + 15) & ~(uintptr_t)15);

    hipMemsetAsync(deg, 0, NN * sizeof(int), stream);

    prep_w<<<(128 * KK) / 256, 256, 0, stream>>>(W, Whi, Wlo);
    count_deg<<<(EE + 255) / 256, 256, 0, stream>>>(dst, pos, deg);
    scan1<<<NB, 256, 0, stream>>>(deg, bsum);
    scan2<<<1, 256, 0, stream>>>(bsum, boff, offs);
    scan3<<<NB, 256, 0, stream>>>(deg, boff, offs, cur);
    fill_edges<<<(EE + 255) / 256, 256, 0, stream>>>(src, dst, pos, dist, cur, elist);
    gather_agg<<<(NN * 64) / 256, 256, 0, stream>>>(h, elist, offs, Xhi, Xlo);
    gemm_mfma<<<NPAD / BM, 256, 0, stream>>>(h, Xhi, Xlo, Whi, Wlo, bias, gamma,
                                             beta, (float*)d_out);
}